// Round 4
// baseline (384.942 us; speedup 1.0000x reference)
//
#include <hip/hip_runtime.h>
#include <math.h>

#define BLOCK 512
#define NWAVES (BLOCK / 64)
#define NV 16              // float4 chunks/thread: 512*16*4 = 32768 >= d
#define SEGCAP 1024        // per-wave candidate segment (raw x), 8*4KB = 32 KB
#define FCAP 4096          // final candidate array (u values), 16 KB
#define NREG 12            // wave0 register-resident candidates: 64*12 = 768

__device__ __forceinline__ float waveAllMax(float v) {
#pragma unroll
    for (int off = 1; off < 64; off <<= 1)
        v = fmaxf(v, __shfl_xor(v, off, 64));
    return v;
}
__device__ __forceinline__ float waveReduceSum(float v) {
#pragma unroll
    for (int off = 32; off > 0; off >>= 1)
        v += __shfl_down(v, off, 64);
    return v;
}

// In-place wave-local compaction of seg[0..cnt) keeping v >= thr.
// Safe: writes land at indices <= already-read window (same-wave DS ops are
// ordered), future read windows start past all writes.
__device__ __forceinline__ int wavePrune(float* seg, int cnt, float thr, int lane) {
    int newcnt = 0;
    for (int base = 0; base < cnt; base += 64) {
        int idx = base + lane;
        bool valid = idx < cnt;
        float v = valid ? seg[idx] : -INFINITY;
        bool keep = valid && (v >= thr);
        unsigned long long mask = __ballot(keep);
        if (keep) {
            int pos = newcnt + (int)__popcll(mask & ((1ull << lane) - 1ull));
            seg[pos] = v;
        }
        newcnt += (int)__popcll(mask);
    }
    return newcnt;
}

// One block per row, streaming: no whole-row register residency. Candidates
// (x >= running_wavemax - 2, a superset of x >= rowmax - 2 for ANY input) are
// ballot-compacted into per-wave LDS segments with a register count — zero
// LDS atomics in the hot loop. After the block max, segments are exact-pruned
// into one final array; wave 0 bisects f(tau)=sum max(u-tau,0)^2=1 and then
// applies the exact closed form tau* = mean - sqrt((1-ss)/k) (identical to
// the reference's sorted-cumsum formula; absmax 0.0 in R1-R3).
// launch_bounds(512,6): 85-VGPR cap -> 3 blocks/CU, staggered phases.
__global__ __launch_bounds__(BLOCK, 6) void tsallis15_kernel(
    const float* __restrict__ x, const int* __restrict__ tgt,
    float* __restrict__ out, int n, int d, float inv_n)
{
    __shared__ float s_seg[NWAVES][SEGCAP];
    __shared__ float s_final[FCAP];
    __shared__ float s_red[NWAVES];
    __shared__ int   s_fcnt;
    __shared__ int   s_flag;
    __shared__ float s_bcast;

    const int row  = blockIdx.x;
    const int t    = threadIdx.x;
    const int lane = t & 63;
    const int wave = t >> 6;
    const float* __restrict__ xr = x + (size_t)row * (size_t)d;

    if (t == 0) { s_fcnt = 0; s_flag = 0; }

    float* seg = &s_seg[wave][0];
    float wmax = -INFINITY;
    int   cnt  = 0;
    bool  ovf  = false;

    // ---- streaming load + running-max filter (single HBM pass) ----
    for (int i0 = 0; i0 < NV; i0 += 4) {
        float4 c[4];
#pragma unroll
        for (int q = 0; q < 4; ++q) {
            int e = ((i0 + q) * BLOCK + t) * 4;
            if (e + 4 <= d) {
                c[q] = *reinterpret_cast<const float4*>(xr + e);
            } else {
                float4 v = make_float4(-INFINITY, -INFINITY, -INFINITY, -INFINITY);
                if (e < d)     v.x = xr[e];
                if (e + 1 < d) v.y = xr[e + 1];
                if (e + 2 < d) v.z = xr[e + 2];
                c[q] = v;
            }
        }
        float m = -INFINITY;
#pragma unroll
        for (int q = 0; q < 4; ++q)
            m = fmaxf(m, fmaxf(fmaxf(c[q].x, c[q].y), fmaxf(c[q].z, c[q].w)));
        wmax = fmaxf(wmax, waveAllMax(m));        // wave-uniform running max
        const float thr = wmax - 2.0f;
#pragma unroll
        for (int q = 0; q < 4; ++q) {
            float vals[4] = { c[q].x, c[q].y, c[q].z, c[q].w };
#pragma unroll
            for (int s = 0; s < 4; ++s) {
                float v = vals[s];
                bool pred = (v >= thr);
                unsigned long long mask = __ballot(pred);
                if (mask) {                        // wave-uniform
                    int pc = (int)__popcll(mask);
                    if (cnt + pc > SEGCAP) {       // wave-uniform
                        cnt = wavePrune(seg, cnt, thr, lane);
                        if (cnt + pc > SEGCAP) ovf = true;
                    }
                    if (!ovf) {
                        if (pred) {
                            int pos = cnt + (int)__popcll(mask & ((1ull << lane) - 1ull));
                            seg[pos] = v;
                        }
                        cnt += pc;
                    }
                }
            }
        }
    }

    // ---- block max ----
    if (lane == 0) {
        s_red[wave] = wmax;
        if (ovf) s_flag = 1;
    }
    __syncthreads();
    if (wave == 0) {
        float v = (lane < NWAVES) ? s_red[lane] : -INFINITY;
        v = waveAllMax(v);
        if (lane == 0) s_bcast = v;
    }
    __syncthreads();
    const float rowmax = s_bcast;
    const float thrF   = rowmax - 2.0f;

    if (s_flag == 0) {
        // ---- exact prune: segments -> s_final as u=(x-rowmax)/2 ----
        for (int base = 0; base < cnt; base += 64) {
            int idx = base + lane;
            float v = (idx < cnt) ? seg[idx] : -INFINITY;
            bool keep = (v >= thrF);
            unsigned long long mask = __ballot(keep);
            if (mask) {
                int bpos;
                if (lane == 0) bpos = atomicAdd(&s_fcnt, (int)__popcll(mask));
                bpos = __shfl(bpos, 0, 64);
                if (keep) {
                    int pos = bpos + (int)__popcll(mask & ((1ull << lane) - 1ull));
                    if (pos < FCAP) s_final[pos] = (v - rowmax) * 0.5f;
                }
            }
        }
    } else {
        // ---- rare fallback: exact rebuild from (cache-warm) row ----
        for (int i = 0; i < NV; ++i) {
            int e = (i * BLOCK + t) * 4;
            float4 c = make_float4(-INFINITY, -INFINITY, -INFINITY, -INFINITY);
            if (e + 4 <= d) c = *reinterpret_cast<const float4*>(xr + e);
            else {
                if (e < d)     c.x = xr[e];
                if (e + 1 < d) c.y = xr[e + 1];
                if (e + 2 < d) c.z = xr[e + 2];
            }
            float vals[4] = { c.x, c.y, c.z, c.w };
#pragma unroll
            for (int s = 0; s < 4; ++s) {
                float v = vals[s];
                bool keep = (v >= thrF);
                unsigned long long mask = __ballot(keep);
                if (mask) {
                    int bpos;
                    if (lane == 0) bpos = atomicAdd(&s_fcnt, (int)__popcll(mask));
                    bpos = __shfl(bpos, 0, 64);
                    if (keep) {
                        int pos = bpos + (int)__popcll(mask & ((1ull << lane) - 1ull));
                        if (pos < FCAP) s_final[pos] = (v - rowmax) * 0.5f;
                    }
                }
            }
        }
    }
    __syncthreads();

    // ---- wave 0: register-resident root-find + loss terms ----
    if (wave == 0) {
        // independent gather chain issued early; consumed at the very end
        const float xt = (lane == 0) ? xr[tgt[row]] : 0.0f;

        const int k = min(s_fcnt, FCAP);

        float ur[NREG];
#pragma unroll
        for (int j = 0; j < NREG; ++j) {
            int idx = lane + 64 * j;
            ur[j] = (idx < k) ? s_final[idx] : -1e30f;  // sentinel: never in support
        }

        // bisection: f monotone decreasing, f(-1)>=1>=f(0), tau* in [-1,0]
        float lo = -1.0f, hi = 0.0f;
        for (int it = 0; it < 18; ++it) {
            float tau = 0.5f * (lo + hi);
            float acc = 0.0f;
#pragma unroll
            for (int j = 0; j < NREG; ++j) {
                float u = ur[j] - tau;
                acc += (u > 0.0f) ? u * u : 0.0f;
            }
            for (int j = 64 * NREG + lane; j < k; j += 64) {  // tail (usually 0-trip)
                float u = s_final[j] - tau;
                if (u > 0.0f) acc += u * u;
            }
            float tot = waveReduceSum(acc);
            tot = __shfl(tot, 0, 64);
            if (tot >= 1.0f) lo = tau; else hi = tau;
        }
        const float tau_b = 0.5f * (lo + hi);

        // exact closed form on identified support: tau* = mean - sqrt((1-ss)/k)
        float s1 = 0.0f, s2 = 0.0f, sc = 0.0f;
#pragma unroll
        for (int j = 0; j < NREG; ++j) {
            float u = ur[j];
            if (u > tau_b) { s1 += u; s2 += u * u; sc += 1.0f; }
        }
        for (int j = 64 * NREG + lane; j < k; j += 64) {
            float u = s_final[j];
            if (u > tau_b) { s1 += u; s2 += u * u; sc += 1.0f; }
        }
        s1 = waveReduceSum(s1); s1 = __shfl(s1, 0, 64);
        s2 = waveReduceSum(s2); s2 = __shfl(s2, 0, 64);
        sc = waveReduceSum(sc); sc = __shfl(sc, 0, 64);
        float mean  = s1 / sc;
        float ss    = s2 - s1 * mean;              // sum of squared deviations
        float delta = (1.0f - ss) / sc;
        if (delta < 0.0f) delta = 0.0f;
        const float tau_star = mean - sqrtf(delta);

        // loss terms: sum p^{3/2} = sum u^3;  dot(p, x) with x = 2u + rowmax
        float p32 = 0.0f, dot = 0.0f;
#pragma unroll
        for (int j = 0; j < NREG; ++j) {
            float u = ur[j] - tau_star;
            if (u > 0.0f) {
                float p = u * u;
                p32 += p * u;
                dot += p * (2.0f * ur[j] + rowmax);
            }
        }
        for (int j = 64 * NREG + lane; j < k; j += 64) {
            float uc = s_final[j];
            float u  = uc - tau_star;
            if (u > 0.0f) {
                float p = u * u;
                p32 += p * u;
                dot += p * (2.0f * uc + rowmax);
            }
        }
        p32 = waveReduceSum(p32);
        dot = waveReduceSum(dot);
        if (lane == 0) {
            float loss = (1.0f - p32) * (4.0f / 3.0f) + dot - xt;
            atomicAdd(out, loss * inv_n);
        }
    }
}

extern "C" void kernel_launch(void* const* d_in, const int* in_sizes, int n_in,
                              void* d_out, int out_size, void* d_ws, size_t ws_size,
                              hipStream_t stream) {
    const float* x   = (const float*)d_in[0];
    const int*   tgt = (const int*)d_in[1];
    float*       out = (float*)d_out;

    const int n = in_sizes[1];
    const int d = in_sizes[0] / n;

    hipMemsetAsync(out, 0, (size_t)out_size * sizeof(float), stream);
    tsallis15_kernel<<<n, BLOCK, 0, stream>>>(x, tgt, out, n, d, 1.0f / (float)n);
}